// Round 6
// baseline (793.701 us; speedup 1.0000x reference)
//
#include <hip/hip_runtime.h>
#include <hip/hip_cooperative_groups.h>
#include <math.h>

namespace cg = cooperative_groups;

// Problem constants (from reference)
#define N_SAMP 200000
#define D_     128
#define T_     8
#define P_     2000
#define NP_    9
#define H_     2048
#define MPAD   2048          // padded M for guard-free MFMA GEMM
#define NSEG   16000
#define NSEGP  16384         // padded segment count for scan

// ---------------------------------------------------------------------------
// Workspace layout (bytes). h2 overlays {fphi,fplo,w1thi,w1tlo} (dead after
// GEMM1; exactly 16,777,216 B). Total ~59.5 MB.
// ---------------------------------------------------------------------------
#define OFF_CNT     0                  // 16384 int
#define OFF_CURSOR  65536              // 16384 int
#define OFF_OFFS    131072             // 16384 int
#define OFF_FIRST   196608             // 2000 int (pad 8192)
#define OFF_PERM    204800             // 200000 int
#define OFF_TMEAN   1004800            // 1024 f32
#define OFF_TSUM    1008896            // 1024 f32
#define OFF_TCNT    1012992            // 8 f32 (pad)
#define OFF_PTSUM   1013760            // 16000*128 f32 = 8,192,000
#define OFF_FPHI    9205760            // 2048*1024 bf16 = 4,194,304
#define OFF_FPLO    13400064
#define OFF_W1THI   17594368
#define OFF_W1TLO   21788672
#define OFF_H1HI    25982976           // 2048*2048 bf16 = 8,388,608
#define OFF_H1LO    34371584
#define OFF_W2THI   42760192
#define OFF_W2TLO   51148800
#define OFF_H2      OFF_FPHI           // overlay (16,777,216 B exactly)

typedef __attribute__((ext_vector_type(8))) short bf16x8;
typedef __attribute__((ext_vector_type(4))) float f32x4;

// bf16 split helpers (bit ops, RNE)
__device__ __forceinline__ unsigned f2bf_rne(float x) {
    unsigned b = __float_as_uint(x);
    return (b + 0x7fffu + ((b >> 16) & 1u)) >> 16;
}
__device__ __forceinline__ float bf2f(unsigned u) {
    return __uint_as_float(u << 16);
}

// async global->LDS, 16B/lane: LDS dest = wave-uniform base + lane*16 [m97/m104]
__device__ __forceinline__ void gload16(const void* g, void* l) {
    __builtin_amdgcn_global_load_lds(
        (const __attribute__((address_space(1))) unsigned int*)g,
        (__attribute__((address_space(3))) unsigned int*)l, 16, 0, 0);
}

// ---------------------------------------------------------------------------
// Kernel 1 (cooperative): the ENTIRE fingerprint pipeline in one dispatch.
// 512 blocks x 256 threads (co-resident: 2 blocks/CU, tiny VGPR/LDS).
// Phases separated by grid.sync(); replaces 9 graph nodes (3 memsets + 6
// kernels) whose ~12us/node launch gaps dominated R5's non-GEMM time.
// NO early returns anywhere (every thread reaches every grid.sync).
// ---------------------------------------------------------------------------
__global__ __launch_bounds__(256) void fingerprint_coop(
    const float* __restrict__ motion_z, const int* __restrict__ tasks,
    const int* __restrict__ tmask, const int* __restrict__ pids,
    const int* __restrict__ pmask, const float* __restrict__ phenos,
    int* __restrict__ cnt, int* __restrict__ cursor, int* __restrict__ offs,
    int* __restrict__ first, int* __restrict__ perm,
    float* __restrict__ tsum, float* __restrict__ tcnt,
    float* __restrict__ tmean, float* __restrict__ pt_sum,
    unsigned short* __restrict__ fphi, unsigned short* __restrict__ fplo,
    float* __restrict__ uni)
{
    cg::grid_group grid = cg::this_grid();
    __shared__ int part[256];
    int tid  = threadIdx.x;
    int gtid = blockIdx.x * 256 + tid;
    int gsz  = gridDim.x * 256;           // 131072

    // P0: init (replaces 3 memsets; ws is poisoned 0xAA before every launch)
    for (int i = gtid; i < NSEGP; i += gsz) { cnt[i] = 0; cursor[i] = 0; }
    for (int i = gtid; i < P_;    i += gsz) first[i] = 0x7fffffff;
    for (int i = gtid; i < 1024;  i += gsz) tsum[i] = 0.f;
    for (int i = gtid; i < 8;     i += gsz) tcnt[i] = 0.f;
    grid.sync();

    // P1: histogram + first-valid-index (~50k int atomics)
    for (int i = gtid; i < N_SAMP; i += gsz)
        if (tmask[i] == 1 && pmask[i] == 1) {
            int p = pids[i];
            atomicAdd(&cnt[p * T_ + tasks[i]], 1);
            atomicMin(&first[p], i);
        }
    grid.sync();

    // P2: exclusive scan of 16384 counts (block 0 only; others wait at sync)
    if (blockIdx.x == 0) {
        int base = tid * 64, s = 0;
#pragma unroll 8
        for (int j = 0; j < 64; ++j) s += cnt[base + j];
        part[tid] = s;
        __syncthreads();
        for (int d = 1; d < 256; d <<= 1) {
            int v = (tid >= d) ? part[tid - d] : 0;
            __syncthreads();
            part[tid] += v;
            __syncthreads();
        }
        int run = (tid > 0) ? part[tid - 1] : 0;
        for (int j = 0; j < 64; ++j) { offs[base + j] = run; run += cnt[base + j]; }
    }
    grid.sync();

    // P3: scatter row indices into per-segment contiguous lists
    for (int i = gtid; i < N_SAMP; i += gsz)
        if (tmask[i] == 1 && pmask[i] == 1) {
            int seg = pids[i] * T_ + tasks[i];
            int pos = atomicAdd(&cursor[seg], 1);
            perm[offs[seg] + pos] = i;
        }
    grid.sync();

    // P4: per-cell gather-reduce (one wave per cell; coalesced 512B rows)
    {
        int wid0 = gtid >> 6, lane = tid & 63, nw = gsz >> 6;   // 2048 waves
        for (int c = wid0; c < NSEG; c += nw) {
            int n = cnt[c], base = offs[c];
            float2 acc = make_float2(0.f, 0.f);
            for (int r = 0; r < n; ++r) {
                int idx = perm[base + r];
                float2 v = *(const float2*)&motion_z[(size_t)idx * D_ + lane * 2];
                acc.x += v.x; acc.y += v.y;
            }
            *(float2*)&pt_sum[(size_t)c * D_ + lane * 2] = acc;
        }
    }
    grid.sync();

    // P5: task-sum partials (125 chunks of 16 patients; atomics into tsum)
    for (int chunk = blockIdx.x; chunk < 125; chunk += gridDim.x) {
        int p0 = chunk * 16;
        float4 acc = make_float4(0.f, 0.f, 0.f, 0.f);
        for (int pl = 0; pl < 16; ++pl) {
            float4 v = *(const float4*)&pt_sum[(size_t)(p0 + pl) * 1024 + tid * 4];
            acc.x += v.x; acc.y += v.y; acc.z += v.z; acc.w += v.w;
        }
        atomicAdd(&tsum[tid * 4 + 0], acc.x);
        atomicAdd(&tsum[tid * 4 + 1], acc.y);
        atomicAdd(&tsum[tid * 4 + 2], acc.z);
        atomicAdd(&tsum[tid * 4 + 3], acc.w);
        if (tid < 128) {
            int p = p0 + (tid >> 3), t = tid & 7;
            atomicAdd(&tcnt[t], (float)cnt[p * 8 + t]);
        }
    }
    grid.sync();

    // P6: tmean divide + first-valid pheno gather
    for (int e = gtid; e < 1024 + P_ * NP_; e += gsz) {
        if (e < 1024) {
            tmean[e] = tsum[e] / fmaxf(tcnt[e >> 7], 1.0f);
        } else {
            int g = e - 1024;
            int p = g / NP_, j = g - p * NP_;
            int idx = first[p];
            if (idx > N_SAMP - 1) idx = N_SAMP - 1;
            uni[g] = phenos[(size_t)idx * NP_ + j];
        }
    }
    grid.sync();

    // P7: finalize fingerprint -> bf16 hi/lo, rows padded to 2048 (zeros)
    for (int e = gtid; e < MPAD * 1024; e += gsz) {
        int p = e >> 10, col = e & 1023;
        float v = 0.f;
        if (p < P_) {
            int c = cnt[p * T_ + (col >> 7)];
            v = (c > 0) ? pt_sum[e] / (float)c : tmean[col];
        }
        unsigned hi = f2bf_rne(v);
        fphi[e] = (unsigned short)hi;
        fplo[e] = (unsigned short)f2bf_rne(v - bf2f(hi));
    }
}

// ---------------------------------------------------------------------------
// Kernel 2: BOTH weight transposes+splits in one dispatch.
// id<2048: W1 [1024][2048] tiles; else W2 [2048][2048] tiles.
// ---------------------------------------------------------------------------
__global__ __launch_bounds__(256) void conv_w_both(
    const float* __restrict__ W1, const float* __restrict__ W2,
    unsigned short* __restrict__ w1hi, unsigned short* __restrict__ w1lo,
    unsigned short* __restrict__ w2hi, unsigned short* __restrict__ w2lo)
{
    __shared__ float tile[32][33];
    int id = blockIdx.x;
    const float* W; unsigned short *Whi, *Wlo; int K;
    if (id < 2048) { W = W1; Whi = w1hi; Wlo = w1lo; K = 1024; }
    else { id -= 2048; W = W2; Whi = w2hi; Wlo = w2lo; K = 2048; }
    int bx = id & 63, by = id >> 6;
    int k0 = by * 32, n0 = bx * 32;
    const int N = 2048;
    int r = threadIdx.x >> 3, c4 = (threadIdx.x & 7) * 4;
    float4 v = *(const float4*)&W[(size_t)(k0 + r) * N + n0 + c4];
    tile[r][c4 + 0] = v.x; tile[r][c4 + 1] = v.y;
    tile[r][c4 + 2] = v.z; tile[r][c4 + 3] = v.w;
    __syncthreads();
    unsigned short hi[4], lo[4];
#pragma unroll
    for (int q = 0; q < 4; ++q) {
        float x = tile[c4 + q][r];
        unsigned h = f2bf_rne(x);
        hi[q] = (unsigned short)h;
        lo[q] = (unsigned short)f2bf_rne(x - bf2f(h));
    }
    size_t o = (size_t)(n0 + r) * K + k0 + c4;
    *(ushort4*)&Whi[o] = make_ushort4(hi[0], hi[1], hi[2], hi[3]);
    *(ushort4*)&Wlo[o] = make_ushort4(lo[0], lo[1], lo[2], lo[3]);
}

// ---------------------------------------------------------------------------
// Kernel 3: MFMA split-precision GEMM (R3-measured config) + XCD swizzle.
// 128x128 tile, 4 waves (64x64), double-buffered 64KB fragment-ordered LDS,
// global_load_lds staging. SQ_LDS_BANK_CONFLICT = 0 (R3/R5-verified).
// 1-D grid of 256; bijective XCD swizzle (256 % 8 == 0, q=32).
// ---------------------------------------------------------------------------
template<int OUTF32>
__global__ __launch_bounds__(256, 1) void gemm_split(
    const unsigned short* __restrict__ Ahi, const unsigned short* __restrict__ Alo,
    const unsigned short* __restrict__ Bhi, const unsigned short* __restrict__ Blo,
    const float* __restrict__ bias,
    float* __restrict__ Cf, unsigned short* __restrict__ Chi,
    unsigned short* __restrict__ Clo, int K)
{
    __shared__ __align__(16) char lds[2][4][8192];   // 64 KiB
    int tid  = threadIdx.x;
    int lane = tid & 63, w = tid >> 6;
    int wr = w >> 1, wc = w & 1;
    int wg = blockIdx.x;
    int sw = ((wg & 7) << 5) + (wg >> 3);            // XCD-contiguous chunks
    int row0 = (sw >> 4) * 128, col0 = (sw & 15) * 128;

    // per-lane fragment source coordinates (lane l holds X[l&15][k0+(l>>4)*8..+7])
    int fr = lane & 15;
    int fk = (lane >> 4) * 8;

    const unsigned short* srcs[4] = {Ahi, Alo, Bhi, Blo};
    int base0[4] = {row0, row0, col0, col0};

    auto STAGE = [&](int buf, int t) {
        int k0 = t * 32;
#pragma unroll
        for (int pc = 0; pc < 4; ++pc) {
#pragma unroll
            for (int rep = 0; rep < 2; ++rep) {
                int tile = rep * 4 + w;                       // wave-uniform
                const unsigned short* g =
                    srcs[pc] + (size_t)(base0[pc] + tile * 16 + fr) * K + k0 + fk;
                gload16(g, &lds[buf][pc][tile * 1024]);       // uniform base
            }
        }
    };

    f32x4 acc[4][4] = {};
    int nt = K / 32;
    STAGE(0, 0);
    __syncthreads();
    int cur = 0;
    int lo16 = lane * 16;

    for (int t = 0; t < nt; ++t) {
        if (t + 1 < nt) STAGE(cur ^ 1, t + 1);
        bf16x8 ah[4], al[4], bh[4], bl[4];
#pragma unroll
        for (int i = 0; i < 4; ++i) {
            ah[i] = *(const bf16x8*)&lds[cur][0][(wr * 4 + i) * 1024 + lo16];
            al[i] = *(const bf16x8*)&lds[cur][1][(wr * 4 + i) * 1024 + lo16];
        }
#pragma unroll
        for (int j = 0; j < 4; ++j) {
            bh[j] = *(const bf16x8*)&lds[cur][2][(wc * 4 + j) * 1024 + lo16];
            bl[j] = *(const bf16x8*)&lds[cur][3][(wc * 4 + j) * 1024 + lo16];
        }
#pragma unroll
        for (int i = 0; i < 4; ++i)
#pragma unroll
            for (int j = 0; j < 4; ++j) {
                acc[i][j] = __builtin_amdgcn_mfma_f32_16x16x32_bf16(ah[i], bh[j], acc[i][j], 0, 0, 0);
                acc[i][j] = __builtin_amdgcn_mfma_f32_16x16x32_bf16(ah[i], bl[j], acc[i][j], 0, 0, 0);
                acc[i][j] = __builtin_amdgcn_mfma_f32_16x16x32_bf16(al[i], bh[j], acc[i][j], 0, 0, 0);
            }
        __syncthreads();     // drains staged loads + frees cur for next stage
        cur ^= 1;
    }

    // Epilogue: C/D layout col=lane&15, row=(lane>>4)*4+reg  [m89-verified]
#pragma unroll
    for (int i = 0; i < 4; ++i) {
        int r = row0 + wr * 64 + i * 16 + (lane >> 4) * 4;
#pragma unroll
        for (int j = 0; j < 4; ++j) {
            int c = col0 + wc * 64 + j * 16 + (lane & 15);
            float bv = bias[c];
#pragma unroll
            for (int q = 0; q < 4; ++q) {
                float x = fmaxf(acc[i][j][q] + bv, 0.f);
                size_t o = (size_t)(r + q) * H_ + c;
                if (OUTF32) {
                    Cf[o] = x;
                } else {
                    unsigned hb = f2bf_rne(x);
                    Chi[o] = (unsigned short)hb;
                    Clo[o] = (unsigned short)f2bf_rne(x - bf2f(hb));
                }
            }
        }
    }
}

// ---------------------------------------------------------------------------
// Kernel 4: head GEMM + sigmoid, W3 staged in LDS.
// ---------------------------------------------------------------------------
__global__ __launch_bounds__(256) void out_head(
    const float* __restrict__ h2, const float* __restrict__ W3,
    const float* __restrict__ b3, float* __restrict__ out,
    float* __restrict__ latent)
{
    __shared__ float w3s[H_ * NP_];            // 73,728 B
    int tid = threadIdx.x;
    for (int e = tid * 4; e < H_ * NP_; e += 1024)
        *(float4*)&w3s[e] = *(const float4*)&W3[e];
    __syncthreads();

    int wid  = blockIdx.x * 4 + (tid >> 6);
    int lane = tid & 63;
    if (wid >= P_) return;
    const float* hrow = h2 + (size_t)wid * H_;
    float acc[NP_] = {};
    for (int k = lane; k < H_; k += 64) {
        float h = hrow[k];
#pragma unroll
        for (int j = 0; j < NP_; ++j) acc[j] = fmaf(h, w3s[k * NP_ + j], acc[j]);
    }
#pragma unroll
    for (int off = 32; off > 0; off >>= 1)
#pragma unroll
        for (int j = 0; j < NP_; ++j) acc[j] += __shfl_down(acc[j], off);
    if (lane == 0) {
#pragma unroll
        for (int j = 0; j < NP_; ++j) {
            float v = acc[j] + b3[j];
            latent[wid * NP_ + j] = v;
            out[wid * NP_ + j]    = 1.f / (1.f + expf(-v));
        }
    }
}

// ---------------------------------------------------------------------------
extern "C" void kernel_launch(void* const* d_in, const int* in_sizes, int n_in,
                              void* d_out, int out_size, void* d_ws, size_t ws_size,
                              hipStream_t stream)
{
    const float* motion_z = (const float*)d_in[0];
    const int*   tasks    = (const int*)d_in[1];
    const int*   tmask    = (const int*)d_in[2];
    const int*   pids     = (const int*)d_in[3];
    const float* phenos   = (const float*)d_in[4];
    const int*   pmask    = (const int*)d_in[5];
    const float* W1 = (const float*)d_in[6];
    const float* b1 = (const float*)d_in[7];
    const float* W2 = (const float*)d_in[8];
    const float* b2 = (const float*)d_in[9];
    const float* W3 = (const float*)d_in[10];
    const float* b3 = (const float*)d_in[11];

    char* ws = (char*)d_ws;
    int*            cnt    = (int*)  (ws + OFF_CNT);
    int*            cursor = (int*)  (ws + OFF_CURSOR);
    int*            offs   = (int*)  (ws + OFF_OFFS);
    int*            first  = (int*)  (ws + OFF_FIRST);
    int*            perm   = (int*)  (ws + OFF_PERM);
    float*          tmean  = (float*)(ws + OFF_TMEAN);
    float*          tsum   = (float*)(ws + OFF_TSUM);
    float*          tcnt   = (float*)(ws + OFF_TCNT);
    float*          pt_sum = (float*)(ws + OFF_PTSUM);
    unsigned short* fphi   = (unsigned short*)(ws + OFF_FPHI);
    unsigned short* fplo   = (unsigned short*)(ws + OFF_FPLO);
    unsigned short* w1thi  = (unsigned short*)(ws + OFF_W1THI);
    unsigned short* w1tlo  = (unsigned short*)(ws + OFF_W1TLO);
    unsigned short* h1hi   = (unsigned short*)(ws + OFF_H1HI);
    unsigned short* h1lo   = (unsigned short*)(ws + OFF_H1LO);
    unsigned short* w2thi  = (unsigned short*)(ws + OFF_W2THI);
    unsigned short* w2tlo  = (unsigned short*)(ws + OFF_W2TLO);
    float*          h2     = (float*)(ws + OFF_H2);

    float* out    = (float*)d_out;
    float* uni    = out + P_ * NP_;
    float* latent = out + 2 * P_ * NP_;

    // Node 1: entire fingerprint pipeline (cooperative, 7 grid syncs)
    void* cargs[] = {
        (void*)&motion_z, (void*)&tasks, (void*)&tmask, (void*)&pids,
        (void*)&pmask, (void*)&phenos, (void*)&cnt, (void*)&cursor,
        (void*)&offs, (void*)&first, (void*)&perm, (void*)&tsum,
        (void*)&tcnt, (void*)&tmean, (void*)&pt_sum, (void*)&fphi,
        (void*)&fplo, (void*)&uni};
    hipLaunchCooperativeKernel((void*)fingerprint_coop, dim3(512), dim3(256),
                               cargs, 0, stream);

    // Node 2: both weight transpose+splits
    conv_w_both<<<6144, 256, 0, stream>>>(W1, W2, w1thi, w1tlo, w2thi, w2tlo);

    // Node 3: GEMM1 fingerprint[2048,1024] @ W1 -> h1 (relu, bf16 hi/lo out)
    gemm_split<0><<<256, 256, 0, stream>>>(
        fphi, fplo, w1thi, w1tlo, b1, nullptr, h1hi, h1lo, 1024);
    // Node 4: GEMM2 h1[2048,2048] @ W2 -> h2 (relu, f32 out)
    gemm_split<1><<<256, 256, 0, stream>>>(
        h1hi, h1lo, w2thi, w2tlo, b2, h2, nullptr, nullptr, H_);

    // Node 5: head + sigmoid
    out_head<<<P_ / 4, 256, 0, stream>>>(h2, W3, b3, out, latent);
}

// Round 7
// 438.231 us; speedup vs baseline: 1.8111x; 1.8111x over previous
//
#include <hip/hip_runtime.h>
#include <math.h>

// Problem constants (from reference)
#define N_SAMP 200000
#define D_     128
#define T_     8
#define P_     2000
#define NP_    9
#define H_     2048
#define MPAD   2048          // padded M for guard-free MFMA GEMM
#define NSEG   16000

// ---------------------------------------------------------------------------
// Workspace layout (bytes). Zero region [0, 8268352) covered by ONE memset:
//   pt_sum | cnt(f32) | tsum | tcnt | fmax.  h2 overlays {fphi..w1tlo}
// (dead after GEMM1; exactly 16,777,216 B). Total ~58.6 MB.
// ---------------------------------------------------------------------------
#define OFF_PTSUM   0                  // 16000*128 f32 = 8,192,000
#define OFF_CNT     8192000            // 16000 f32    = 64,000
#define OFF_TSUM    8256000            // 1024 f32     = 4,096
#define OFF_TCNT    8260096            // 8 f32 (pad 256)
#define OFF_FMAX    8260352            // 2000 u32     = 8,000
#define ZERO_BYTES  8268352
#define OFF_FPHI    8268544            // 2048*1024 bf16 = 4,194,304
#define OFF_FPLO    12462848
#define OFF_W1THI   16657152
#define OFF_W1TLO   20851456
#define OFF_H1HI    25045760           // 2048*2048 bf16 = 8,388,608
#define OFF_H1LO    33434368
#define OFF_W2THI   41822976
#define OFF_W2TLO   50211584
#define OFF_H2      OFF_FPHI           // overlay (16,777,216 B exactly)

typedef __attribute__((ext_vector_type(8))) short bf16x8;
typedef __attribute__((ext_vector_type(4))) float f32x4;

// bf16 split helpers (bit ops, RNE)
__device__ __forceinline__ unsigned f2bf_rne(float x) {
    unsigned b = __float_as_uint(x);
    return (b + 0x7fffu + ((b >> 16) & 1u)) >> 16;
}
__device__ __forceinline__ float bf2f(unsigned u) {
    return __uint_as_float(u << 16);
}

// async global->LDS, 16B/lane: LDS dest = wave-uniform base + lane*16 [m97/m104]
__device__ __forceinline__ void gload16(const void* g, void* l) {
    __builtin_amdgcn_global_load_lds(
        (const __attribute__((address_space(1))) unsigned int*)g,
        (__attribute__((address_space(3))) unsigned int*)l, 16, 0, 0);
}

// ---------------------------------------------------------------------------
// Kernel 1: scatter-reduce + first-valid tracking, grid-stride waves.
// fmax[p] = max(N_SAMP - i) over valid rows (zero-init ok; decodes to min i).
// ---------------------------------------------------------------------------
__global__ __launch_bounds__(256) void scatter_pt(
    const float* __restrict__ motion_z, const int* __restrict__ tasks,
    const int* __restrict__ tmask, const int* __restrict__ pids,
    const int* __restrict__ pmask, float* __restrict__ pt_sum,
    float* __restrict__ cnt, unsigned* __restrict__ fmax)
{
    int wid0 = (blockIdx.x * blockDim.x + threadIdx.x) >> 6;
    int lane = threadIdx.x & 63;
    int nw   = (gridDim.x * blockDim.x) >> 6;
    for (int wid = wid0; wid < N_SAMP; wid += nw) {
        if (tmask[wid] != 1 || pmask[wid] != 1) continue;
        int p = pids[wid];
        int seg = p * T_ + tasks[wid];
        if (lane == 0) {
            atomicAdd(&cnt[seg], 1.0f);
            atomicMax(&fmax[p], (unsigned)(N_SAMP - wid));
        }
        float2 v = *(const float2*)&motion_z[(size_t)wid * D_ + lane * 2];
        atomicAdd(&pt_sum[seg * D_ + lane * 2 + 0], v.x);
        atomicAdd(&pt_sum[seg * D_ + lane * 2 + 1], v.y);
    }
}

// ---------------------------------------------------------------------------
// Kernel 2: streaming partial reduce over patients for task mean.
// ---------------------------------------------------------------------------
__global__ __launch_bounds__(256) void tsum_partial(
    const float* __restrict__ pt_sum, const float* __restrict__ cnt,
    float* __restrict__ tsum, float* __restrict__ tcnt)
{
    int p0 = blockIdx.x * 16;
    int tid = threadIdx.x;
    float4 acc = make_float4(0.f, 0.f, 0.f, 0.f);
    for (int pl = 0; pl < 16; ++pl) {
        float4 v = *(const float4*)&pt_sum[(size_t)(p0 + pl) * 1024 + tid * 4];
        acc.x += v.x; acc.y += v.y; acc.z += v.z; acc.w += v.w;
    }
    atomicAdd(&tsum[tid * 4 + 0], acc.x);
    atomicAdd(&tsum[tid * 4 + 1], acc.y);
    atomicAdd(&tsum[tid * 4 + 2], acc.z);
    atomicAdd(&tsum[tid * 4 + 3], acc.w);
    if (tid < 128) {
        int p = p0 + (tid >> 3), t = tid & 7;
        atomicAdd(&tcnt[t], cnt[p * 8 + t]);
    }
}

// ---------------------------------------------------------------------------
// Kernel 3: fused finalize. e < MPAD*1024: fingerprint -> bf16 hi/lo (tmean
// divide inlined: tsum[col]/max(tcnt,1)). Tail: first-valid pheno gather.
// ---------------------------------------------------------------------------
__global__ __launch_bounds__(256) void finalize_fused(
    const float* __restrict__ pt_sum, const float* __restrict__ cnt,
    const float* __restrict__ tsum, const float* __restrict__ tcnt,
    const unsigned* __restrict__ fmax, const float* __restrict__ phenos,
    unsigned short* __restrict__ fphi, unsigned short* __restrict__ fplo,
    float* __restrict__ uni)
{
    int e = blockIdx.x * 256 + threadIdx.x;
    if (e < MPAD * 1024) {
        int p = e >> 10, col = e & 1023;
        float v = 0.f;
        if (p < P_) {
            float c = cnt[p * T_ + (col >> 7)];
            v = (c > 0.f) ? pt_sum[e] / c
                          : tsum[col] / fmaxf(tcnt[col >> 7], 1.0f);
        }
        unsigned hi = f2bf_rne(v);
        fphi[e] = (unsigned short)hi;
        fplo[e] = (unsigned short)f2bf_rne(v - bf2f(hi));
    } else {
        int g = e - MPAD * 1024;
        if (g < P_ * NP_) {
            int p = g / NP_, j = g - p * NP_;
            unsigned fm = fmax[p];
            int idx = fm ? (int)(N_SAMP - fm) : N_SAMP - 1;   // no valid -> clip
            uni[g] = phenos[(size_t)idx * NP_ + j];
        }
    }
}

// ---------------------------------------------------------------------------
// Kernel 4: BOTH weight transposes+splits in one dispatch.
// id<2048: W1 [1024][2048] tiles; else W2 [2048][2048] tiles.
// ---------------------------------------------------------------------------
__global__ __launch_bounds__(256) void conv_w_both(
    const float* __restrict__ W1, const float* __restrict__ W2,
    unsigned short* __restrict__ w1hi, unsigned short* __restrict__ w1lo,
    unsigned short* __restrict__ w2hi, unsigned short* __restrict__ w2lo)
{
    __shared__ float tile[32][33];
    int id = blockIdx.x;
    const float* W; unsigned short *Whi, *Wlo; int K;
    if (id < 2048) { W = W1; Whi = w1hi; Wlo = w1lo; K = 1024; }
    else { id -= 2048; W = W2; Whi = w2hi; Wlo = w2lo; K = 2048; }
    int bx = id & 63, by = id >> 6;
    int k0 = by * 32, n0 = bx * 32;
    const int N = 2048;
    int r = threadIdx.x >> 3, c4 = (threadIdx.x & 7) * 4;
    float4 v = *(const float4*)&W[(size_t)(k0 + r) * N + n0 + c4];
    tile[r][c4 + 0] = v.x; tile[r][c4 + 1] = v.y;
    tile[r][c4 + 2] = v.z; tile[r][c4 + 3] = v.w;
    __syncthreads();
    unsigned short hi[4], lo[4];
#pragma unroll
    for (int q = 0; q < 4; ++q) {
        float x = tile[c4 + q][r];
        unsigned h = f2bf_rne(x);
        hi[q] = (unsigned short)h;
        lo[q] = (unsigned short)f2bf_rne(x - bf2f(h));
    }
    size_t o = (size_t)(n0 + r) * K + k0 + c4;
    *(ushort4*)&Whi[o] = make_ushort4(hi[0], hi[1], hi[2], hi[3]);
    *(ushort4*)&Wlo[o] = make_ushort4(lo[0], lo[1], lo[2], lo[3]);
}

// ---------------------------------------------------------------------------
// Kernel 5: MFMA split-precision GEMM (R3/R5-measured config, no swizzle).
// 128x128 tile, 4 waves (64x64), double-buffered 64KB fragment-ordered LDS,
// global_load_lds staging. SQ_LDS_BANK_CONFLICT = 0 (R3/R5-verified).
// ---------------------------------------------------------------------------
template<int OUTF32>
__global__ __launch_bounds__(256, 1) void gemm_split(
    const unsigned short* __restrict__ Ahi, const unsigned short* __restrict__ Alo,
    const unsigned short* __restrict__ Bhi, const unsigned short* __restrict__ Blo,
    const float* __restrict__ bias,
    float* __restrict__ Cf, unsigned short* __restrict__ Chi,
    unsigned short* __restrict__ Clo, int K)
{
    __shared__ __align__(16) char lds[2][4][8192];   // 64 KiB
    int tid  = threadIdx.x;
    int lane = tid & 63, w = tid >> 6;
    int wr = w >> 1, wc = w & 1;
    int row0 = blockIdx.y * 128, col0 = blockIdx.x * 128;

    // per-lane fragment source coordinates (lane l holds X[l&15][k0+(l>>4)*8..+7])
    int fr = lane & 15;
    int fk = (lane >> 4) * 8;

    const unsigned short* srcs[4] = {Ahi, Alo, Bhi, Blo};
    int base0[4] = {row0, row0, col0, col0};

    auto STAGE = [&](int buf, int t) {
        int k0 = t * 32;
#pragma unroll
        for (int pc = 0; pc < 4; ++pc) {
#pragma unroll
            for (int rep = 0; rep < 2; ++rep) {
                int tile = rep * 4 + w;                       // wave-uniform
                const unsigned short* g =
                    srcs[pc] + (size_t)(base0[pc] + tile * 16 + fr) * K + k0 + fk;
                gload16(g, &lds[buf][pc][tile * 1024]);       // uniform base
            }
        }
    };

    f32x4 acc[4][4] = {};
    int nt = K / 32;
    STAGE(0, 0);
    __syncthreads();
    int cur = 0;
    int lo16 = lane * 16;

    for (int t = 0; t < nt; ++t) {
        if (t + 1 < nt) STAGE(cur ^ 1, t + 1);
        bf16x8 ah[4], al[4], bh[4], bl[4];
#pragma unroll
        for (int i = 0; i < 4; ++i) {
            ah[i] = *(const bf16x8*)&lds[cur][0][(wr * 4 + i) * 1024 + lo16];
            al[i] = *(const bf16x8*)&lds[cur][1][(wr * 4 + i) * 1024 + lo16];
        }
#pragma unroll
        for (int j = 0; j < 4; ++j) {
            bh[j] = *(const bf16x8*)&lds[cur][2][(wc * 4 + j) * 1024 + lo16];
            bl[j] = *(const bf16x8*)&lds[cur][3][(wc * 4 + j) * 1024 + lo16];
        }
#pragma unroll
        for (int i = 0; i < 4; ++i)
#pragma unroll
            for (int j = 0; j < 4; ++j) {
                acc[i][j] = __builtin_amdgcn_mfma_f32_16x16x32_bf16(ah[i], bh[j], acc[i][j], 0, 0, 0);
                acc[i][j] = __builtin_amdgcn_mfma_f32_16x16x32_bf16(ah[i], bl[j], acc[i][j], 0, 0, 0);
                acc[i][j] = __builtin_amdgcn_mfma_f32_16x16x32_bf16(al[i], bh[j], acc[i][j], 0, 0, 0);
            }
        __syncthreads();     // drains staged loads + frees cur for next stage
        cur ^= 1;
    }

    // Epilogue: C/D layout col=lane&15, row=(lane>>4)*4+reg  [m89-verified]
#pragma unroll
    for (int i = 0; i < 4; ++i) {
        int r = row0 + wr * 64 + i * 16 + (lane >> 4) * 4;
#pragma unroll
        for (int j = 0; j < 4; ++j) {
            int c = col0 + wc * 64 + j * 16 + (lane & 15);
            float bv = bias[c];
#pragma unroll
            for (int q = 0; q < 4; ++q) {
                float x = fmaxf(acc[i][j][q] + bv, 0.f);
                size_t o = (size_t)(r + q) * H_ + c;
                if (OUTF32) {
                    Cf[o] = x;
                } else {
                    unsigned hb = f2bf_rne(x);
                    Chi[o] = (unsigned short)hb;
                    Clo[o] = (unsigned short)f2bf_rne(x - bf2f(hb));
                }
            }
        }
    }
}

// ---------------------------------------------------------------------------
// Kernel 6: head GEMM + sigmoid, W3 staged in LDS.
// ---------------------------------------------------------------------------
__global__ __launch_bounds__(256) void out_head(
    const float* __restrict__ h2, const float* __restrict__ W3,
    const float* __restrict__ b3, float* __restrict__ out,
    float* __restrict__ latent)
{
    __shared__ float w3s[H_ * NP_];            // 73,728 B
    int tid = threadIdx.x;
    for (int e = tid * 4; e < H_ * NP_; e += 1024)
        *(float4*)&w3s[e] = *(const float4*)&W3[e];
    __syncthreads();

    int wid  = blockIdx.x * 4 + (tid >> 6);
    int lane = tid & 63;
    if (wid >= P_) return;
    const float* hrow = h2 + (size_t)wid * H_;
    float acc[NP_] = {};
    for (int k = lane; k < H_; k += 64) {
        float h = hrow[k];
#pragma unroll
        for (int j = 0; j < NP_; ++j) acc[j] = fmaf(h, w3s[k * NP_ + j], acc[j]);
    }
#pragma unroll
    for (int off = 32; off > 0; off >>= 1)
#pragma unroll
        for (int j = 0; j < NP_; ++j) acc[j] += __shfl_down(acc[j], off);
    if (lane == 0) {
#pragma unroll
        for (int j = 0; j < NP_; ++j) {
            float v = acc[j] + b3[j];
            latent[wid * NP_ + j] = v;
            out[wid * NP_ + j]    = 1.f / (1.f + expf(-v));
        }
    }
}

// ---------------------------------------------------------------------------
extern "C" void kernel_launch(void* const* d_in, const int* in_sizes, int n_in,
                              void* d_out, int out_size, void* d_ws, size_t ws_size,
                              hipStream_t stream)
{
    const float* motion_z = (const float*)d_in[0];
    const int*   tasks    = (const int*)d_in[1];
    const int*   tmask    = (const int*)d_in[2];
    const int*   pids     = (const int*)d_in[3];
    const float* phenos   = (const float*)d_in[4];
    const int*   pmask    = (const int*)d_in[5];
    const float* W1 = (const float*)d_in[6];
    const float* b1 = (const float*)d_in[7];
    const float* W2 = (const float*)d_in[8];
    const float* b2 = (const float*)d_in[9];
    const float* W3 = (const float*)d_in[10];
    const float* b3 = (const float*)d_in[11];

    char* ws = (char*)d_ws;
    float*          pt_sum = (float*)(ws + OFF_PTSUM);
    float*          cnt    = (float*)(ws + OFF_CNT);
    float*          tsum   = (float*)(ws + OFF_TSUM);
    float*          tcnt   = (float*)(ws + OFF_TCNT);
    unsigned*       fmax   = (unsigned*)(ws + OFF_FMAX);
    unsigned short* fphi   = (unsigned short*)(ws + OFF_FPHI);
    unsigned short* fplo   = (unsigned short*)(ws + OFF_FPLO);
    unsigned short* w1thi  = (unsigned short*)(ws + OFF_W1THI);
    unsigned short* w1tlo  = (unsigned short*)(ws + OFF_W1TLO);
    unsigned short* h1hi   = (unsigned short*)(ws + OFF_H1HI);
    unsigned short* h1lo   = (unsigned short*)(ws + OFF_H1LO);
    unsigned short* w2thi  = (unsigned short*)(ws + OFF_W2THI);
    unsigned short* w2tlo  = (unsigned short*)(ws + OFF_W2TLO);
    float*          h2     = (float*)(ws + OFF_H2);

    float* out    = (float*)d_out;
    float* uni    = out + P_ * NP_;
    float* latent = out + 2 * P_ * NP_;

    // Node 1: single memset covers pt_sum | cnt | tsum | tcnt | fmax
    hipMemsetAsync(ws, 0, ZERO_BYTES, stream);

    // Node 2: scatter + first tracking
    scatter_pt<<<2048, 256, 0, stream>>>(motion_z, tasks, tmask, pids, pmask,
                                         pt_sum, cnt, fmax);
    // Node 3: task-sum partials
    tsum_partial<<<125, 256, 0, stream>>>(pt_sum, cnt, tsum, tcnt);
    // Node 4: finalize fingerprint (tmean inline) + pheno gather
    finalize_fused<<<(MPAD * 1024 + P_ * NP_ + 255) / 256, 256, 0, stream>>>(
        pt_sum, cnt, tsum, tcnt, fmax, phenos, fphi, fplo, uni);

    // Node 5: both weight transpose+splits
    conv_w_both<<<6144, 256, 0, stream>>>(W1, W2, w1thi, w1tlo, w2thi, w2tlo);

    // Node 6: GEMM1 fingerprint[2048,1024] @ W1 -> h1 (relu, bf16 hi/lo out)
    gemm_split<0><<<dim3(16, 16), 256, 0, stream>>>(
        fphi, fplo, w1thi, w1tlo, b1, nullptr, h1hi, h1lo, 1024);
    // Node 7: GEMM2 h1[2048,2048] @ W2 -> h2 (relu, f32 out)
    gemm_split<1><<<dim3(16, 16), 256, 0, stream>>>(
        h1hi, h1lo, w2thi, w2tlo, b2, h2, nullptr, nullptr, H_);

    // Node 8: head + sigmoid
    out_head<<<P_ / 4, 256, 0, stream>>>(h2, W3, b3, out, latent);
}

// Round 8
// 420.790 us; speedup vs baseline: 1.8862x; 1.0414x over previous
//
#include <hip/hip_runtime.h>
#include <math.h>

// Problem constants (from reference)
#define N_SAMP 200000
#define D_     128
#define T_     8
#define P_     2000
#define NP_    9
#define H_     2048
#define MPAD   2048          // padded M for guard-free MFMA GEMM
#define NSEG   16000

// ---------------------------------------------------------------------------
// Workspace layout (bytes). Zero region [0, ZERO_BYTES) covered by ONE memset:
//   pt_sum | cnt(f32) | tsum | tcnt | fmax.  h2 overlays {fphi..w1tlo}
// (dead after GEMM1; exactly 16,777,216 B). Total ~58.6 MB.
// ---------------------------------------------------------------------------
#define OFF_PTSUM   0                  // 16000*128 f32 = 8,192,000
#define OFF_CNT     8192000            // 16000 f32    = 64,000
#define OFF_TSUM    8256000            // 1024 f32     = 4,096
#define OFF_TCNT    8260096            // 8 f32 (pad 256)
#define OFF_FMAX    8260352            // 2000 u32     = 8,000
#define ZERO_BYTES  8268352
#define OFF_FPHI    8268544            // 2048*1024 bf16 = 4,194,304
#define OFF_FPLO    12462848
#define OFF_W1THI   16657152
#define OFF_W1TLO   20851456
#define OFF_H1HI    25045760           // 2048*2048 bf16 = 8,388,608
#define OFF_H1LO    33434368
#define OFF_W2THI   41822976
#define OFF_W2TLO   50211584
#define OFF_H2      OFF_FPHI           // overlay (16,777,216 B exactly)

typedef __attribute__((ext_vector_type(8))) short bf16x8;
typedef __attribute__((ext_vector_type(4))) float f32x4;

// bf16 split helpers (bit ops, RNE)
__device__ __forceinline__ unsigned f2bf_rne(float x) {
    unsigned b = __float_as_uint(x);
    return (b + 0x7fffu + ((b >> 16) & 1u)) >> 16;
}
__device__ __forceinline__ float bf2f(unsigned u) {
    return __uint_as_float(u << 16);
}

// async global->LDS, 16B/lane: LDS dest = wave-uniform base + lane*16 [m97/m104]
__device__ __forceinline__ void gload16(const void* g, void* l) {
    __builtin_amdgcn_global_load_lds(
        (const __attribute__((address_space(1))) unsigned int*)g,
        (__attribute__((address_space(3))) unsigned int*)l, 16, 0, 0);
}

// ---------------------------------------------------------------------------
// Kernel 1: block-compaction scatter. Threads scan masks coalescedly (256
// rows/iter/block), push valid (seg,row) into an LDS list; waves drain the
// list: 512B coalesced motion_z read + 2 atomicAdd/lane into pt_sum.
// cnt/fmax updated by the finder thread. Replaces the one-wave-per-row scan
// (2 serial scalar loads + branch per row per wave) that was latency-bound.
// ---------------------------------------------------------------------------
__global__ __launch_bounds__(256) void scatter_pt(
    const float* __restrict__ motion_z, const int* __restrict__ tasks,
    const int* __restrict__ tmask, const int* __restrict__ pids,
    const int* __restrict__ pmask, float* __restrict__ pt_sum,
    float* __restrict__ cnt, unsigned* __restrict__ fmax)
{
    __shared__ unsigned list[256];
    __shared__ int nvalid;
    int tid  = threadIdx.x;
    int lane = tid & 63;
    int wv   = tid >> 6;
    for (int base = blockIdx.x * 256; base < N_SAMP; base += gridDim.x * 256) {
        if (tid == 0) nvalid = 0;
        __syncthreads();
        int i = base + tid;
        if (i < N_SAMP && tmask[i] == 1 && pmask[i] == 1) {
            int p = pids[i];
            int seg = p * T_ + tasks[i];
            atomicAdd(&cnt[seg], 1.0f);
            atomicMax(&fmax[p], (unsigned)(N_SAMP - i));
            int pos = atomicAdd(&nvalid, 1);
            list[pos] = ((unsigned)seg << 18) | (unsigned)i;   // seg<16384, i<2^18
        }
        __syncthreads();
        int nv = nvalid;
        for (int e = wv; e < nv; e += 4) {
            unsigned pk = list[e];
            int row = (int)(pk & 0x3FFFFu);
            int seg = (int)(pk >> 18);
            float2 v = *(const float2*)&motion_z[(size_t)row * D_ + lane * 2];
            atomicAdd(&pt_sum[seg * D_ + lane * 2 + 0], v.x);
            atomicAdd(&pt_sum[seg * D_ + lane * 2 + 1], v.y);
        }
        __syncthreads();
    }
}

// ---------------------------------------------------------------------------
// Kernel 2 (fused, independent sub-jobs by block range):
//   blocks [0,125)      : task-sum partial reduce (reads pt_sum/cnt)
//   blocks [125,125+6144): weight transpose+split (W1: first 2048, W2: rest)
// ---------------------------------------------------------------------------
__global__ __launch_bounds__(256) void mid_fused(
    const float* __restrict__ pt_sum, const float* __restrict__ cnt,
    float* __restrict__ tsum, float* __restrict__ tcnt,
    const float* __restrict__ W1, const float* __restrict__ W2,
    unsigned short* __restrict__ w1hi, unsigned short* __restrict__ w1lo,
    unsigned short* __restrict__ w2hi, unsigned short* __restrict__ w2lo)
{
    __shared__ float tile[32][33];
    int tid = threadIdx.x;
    if (blockIdx.x < 125) {
        int p0 = blockIdx.x * 16;
        float4 acc = make_float4(0.f, 0.f, 0.f, 0.f);
        for (int pl = 0; pl < 16; ++pl) {
            float4 v = *(const float4*)&pt_sum[(size_t)(p0 + pl) * 1024 + tid * 4];
            acc.x += v.x; acc.y += v.y; acc.z += v.z; acc.w += v.w;
        }
        atomicAdd(&tsum[tid * 4 + 0], acc.x);
        atomicAdd(&tsum[tid * 4 + 1], acc.y);
        atomicAdd(&tsum[tid * 4 + 2], acc.z);
        atomicAdd(&tsum[tid * 4 + 3], acc.w);
        if (tid < 128) {
            int p = p0 + (tid >> 3), t = tid & 7;
            atomicAdd(&tcnt[t], cnt[p * 8 + t]);
        }
        return;
    }
    int id = blockIdx.x - 125;
    const float* W; unsigned short *Whi, *Wlo; int K;
    if (id < 2048) { W = W1; Whi = w1hi; Wlo = w1lo; K = 1024; }
    else { id -= 2048; W = W2; Whi = w2hi; Wlo = w2lo; K = 2048; }
    int bx = id & 63, by = id >> 6;
    int k0 = by * 32, n0 = bx * 32;
    const int N = 2048;
    int r = tid >> 3, c4 = (tid & 7) * 4;
    float4 v = *(const float4*)&W[(size_t)(k0 + r) * N + n0 + c4];
    tile[r][c4 + 0] = v.x; tile[r][c4 + 1] = v.y;
    tile[r][c4 + 2] = v.z; tile[r][c4 + 3] = v.w;
    __syncthreads();
    unsigned short hi[4], lo[4];
#pragma unroll
    for (int q = 0; q < 4; ++q) {
        float x = tile[c4 + q][r];
        unsigned h = f2bf_rne(x);
        hi[q] = (unsigned short)h;
        lo[q] = (unsigned short)f2bf_rne(x - bf2f(h));
    }
    size_t o = (size_t)(n0 + r) * K + k0 + c4;
    *(ushort4*)&Whi[o] = make_ushort4(hi[0], hi[1], hi[2], hi[3]);
    *(ushort4*)&Wlo[o] = make_ushort4(lo[0], lo[1], lo[2], lo[3]);
}

// ---------------------------------------------------------------------------
// Kernel 3: fused finalize, 8 elems/thread (float4 reads, bf16x8 stores).
// blocks [0,1024): fingerprint -> bf16 hi/lo (tmean divide inlined).
// blocks [1024,..): first-valid pheno gather.
// ---------------------------------------------------------------------------
__global__ __launch_bounds__(256) void finalize_fused(
    const float* __restrict__ pt_sum, const float* __restrict__ cnt,
    const float* __restrict__ tsum, const float* __restrict__ tcnt,
    const unsigned* __restrict__ fmax, const float* __restrict__ phenos,
    unsigned short* __restrict__ fphi, unsigned short* __restrict__ fplo,
    float* __restrict__ uni)
{
    if (blockIdx.x < 1024) {
        int e8 = blockIdx.x * 256 + threadIdx.x;     // 8-elem group id
        int e  = e8 * 8;
        int p = e >> 10, col0 = e & 1023;
        int seg = p * T_ + (col0 >> 7);              // all 8 share the task block
        ushort hi[8], lo[8];
        if (p < P_) {
            float c = cnt[seg];
            float4 a = *(const float4*)&pt_sum[e];
            float4 b = *(const float4*)&pt_sum[e + 4];
            float vv[8] = {a.x, a.y, a.z, a.w, b.x, b.y, b.z, b.w};
#pragma unroll
            for (int q = 0; q < 8; ++q) {
                float v;
                if (c > 0.f) v = vv[q] / c;
                else         v = tsum[col0 + q] / fmaxf(tcnt[col0 >> 7], 1.0f);
                unsigned h = f2bf_rne(v);
                hi[q] = (ushort)h;
                lo[q] = (ushort)f2bf_rne(v - bf2f(h));
            }
        } else {
#pragma unroll
            for (int q = 0; q < 8; ++q) { hi[q] = 0; lo[q] = 0; }
        }
        *(ushort4*)&fphi[e]     = make_ushort4(hi[0], hi[1], hi[2], hi[3]);
        *(ushort4*)&fphi[e + 4] = make_ushort4(hi[4], hi[5], hi[6], hi[7]);
        *(ushort4*)&fplo[e]     = make_ushort4(lo[0], lo[1], lo[2], lo[3]);
        *(ushort4*)&fplo[e + 4] = make_ushort4(lo[4], lo[5], lo[6], lo[7]);
    } else {
        int g = (blockIdx.x - 1024) * 256 + threadIdx.x;
        if (g < P_ * NP_) {
            int p = g / NP_, j = g - p * NP_;
            unsigned fm = fmax[p];
            int idx = fm ? (int)(N_SAMP - fm) : N_SAMP - 1;   // no valid -> clip
            uni[g] = phenos[(size_t)idx * NP_ + j];
        }
    }
}

// ---------------------------------------------------------------------------
// Kernel 4: MFMA split-precision GEMM (R3/R5/R7-measured config).
// 128x128 tile, 4 waves (64x64), double-buffered 64KB fragment-ordered LDS,
// global_load_lds staging. SQ_LDS_BANK_CONFLICT = 0 (verified).
// ---------------------------------------------------------------------------
template<int OUTF32>
__global__ __launch_bounds__(256, 1) void gemm_split(
    const unsigned short* __restrict__ Ahi, const unsigned short* __restrict__ Alo,
    const unsigned short* __restrict__ Bhi, const unsigned short* __restrict__ Blo,
    const float* __restrict__ bias,
    float* __restrict__ Cf, unsigned short* __restrict__ Chi,
    unsigned short* __restrict__ Clo, int K)
{
    __shared__ __align__(16) char lds[2][4][8192];   // 64 KiB
    int tid  = threadIdx.x;
    int lane = tid & 63, w = tid >> 6;
    int wr = w >> 1, wc = w & 1;
    int row0 = blockIdx.y * 128, col0 = blockIdx.x * 128;

    // per-lane fragment source coordinates (lane l holds X[l&15][k0+(l>>4)*8..+7])
    int fr = lane & 15;
    int fk = (lane >> 4) * 8;

    const unsigned short* srcs[4] = {Ahi, Alo, Bhi, Blo};
    int base0[4] = {row0, row0, col0, col0};

    auto STAGE = [&](int buf, int t) {
        int k0 = t * 32;
#pragma unroll
        for (int pc = 0; pc < 4; ++pc) {
#pragma unroll
            for (int rep = 0; rep < 2; ++rep) {
                int tile = rep * 4 + w;                       // wave-uniform
                const unsigned short* g =
                    srcs[pc] + (size_t)(base0[pc] + tile * 16 + fr) * K + k0 + fk;
                gload16(g, &lds[buf][pc][tile * 1024]);       // uniform base
            }
        }
    };

    f32x4 acc[4][4] = {};
    int nt = K / 32;
    STAGE(0, 0);
    __syncthreads();
    int cur = 0;
    int lo16 = lane * 16;

    for (int t = 0; t < nt; ++t) {
        if (t + 1 < nt) STAGE(cur ^ 1, t + 1);
        bf16x8 ah[4], al[4], bh[4], bl[4];
#pragma unroll
        for (int i = 0; i < 4; ++i) {
            ah[i] = *(const bf16x8*)&lds[cur][0][(wr * 4 + i) * 1024 + lo16];
            al[i] = *(const bf16x8*)&lds[cur][1][(wr * 4 + i) * 1024 + lo16];
        }
#pragma unroll
        for (int j = 0; j < 4; ++j) {
            bh[j] = *(const bf16x8*)&lds[cur][2][(wc * 4 + j) * 1024 + lo16];
            bl[j] = *(const bf16x8*)&lds[cur][3][(wc * 4 + j) * 1024 + lo16];
        }
#pragma unroll
        for (int i = 0; i < 4; ++i)
#pragma unroll
            for (int j = 0; j < 4; ++j) {
                acc[i][j] = __builtin_amdgcn_mfma_f32_16x16x32_bf16(ah[i], bh[j], acc[i][j], 0, 0, 0);
                acc[i][j] = __builtin_amdgcn_mfma_f32_16x16x32_bf16(ah[i], bl[j], acc[i][j], 0, 0, 0);
                acc[i][j] = __builtin_amdgcn_mfma_f32_16x16x32_bf16(al[i], bh[j], acc[i][j], 0, 0, 0);
            }
        __syncthreads();     // drains staged loads + frees cur for next stage
        cur ^= 1;
    }

    // Epilogue: C/D layout col=lane&15, row=(lane>>4)*4+reg  [m89-verified]
#pragma unroll
    for (int i = 0; i < 4; ++i) {
        int r = row0 + wr * 64 + i * 16 + (lane >> 4) * 4;
#pragma unroll
        for (int j = 0; j < 4; ++j) {
            int c = col0 + wc * 64 + j * 16 + (lane & 15);
            float bv = bias[c];
#pragma unroll
            for (int q = 0; q < 4; ++q) {
                float x = fmaxf(acc[i][j][q] + bv, 0.f);
                size_t o = (size_t)(r + q) * H_ + c;
                if (OUTF32) {
                    Cf[o] = x;
                } else {
                    unsigned hb = f2bf_rne(x);
                    Chi[o] = (unsigned short)hb;
                    Clo[o] = (unsigned short)f2bf_rne(x - bf2f(hb));
                }
            }
        }
    }
}

// ---------------------------------------------------------------------------
// Kernel 5: head GEMM + sigmoid, W3 staged in LDS.
// ---------------------------------------------------------------------------
__global__ __launch_bounds__(256) void out_head(
    const float* __restrict__ h2, const float* __restrict__ W3,
    const float* __restrict__ b3, float* __restrict__ out,
    float* __restrict__ latent)
{
    __shared__ float w3s[H_ * NP_];            // 73,728 B
    int tid = threadIdx.x;
    for (int e = tid * 4; e < H_ * NP_; e += 1024)
        *(float4*)&w3s[e] = *(const float4*)&W3[e];
    __syncthreads();

    int wid  = blockIdx.x * 4 + (tid >> 6);
    int lane = tid & 63;
    if (wid >= P_) return;
    const float* hrow = h2 + (size_t)wid * H_;
    float acc[NP_] = {};
    for (int k = lane; k < H_; k += 64) {
        float h = hrow[k];
#pragma unroll
        for (int j = 0; j < NP_; ++j) acc[j] = fmaf(h, w3s[k * NP_ + j], acc[j]);
    }
#pragma unroll
    for (int off = 32; off > 0; off >>= 1)
#pragma unroll
        for (int j = 0; j < NP_; ++j) acc[j] += __shfl_down(acc[j], off);
    if (lane == 0) {
#pragma unroll
        for (int j = 0; j < NP_; ++j) {
            float v = acc[j] + b3[j];
            latent[wid * NP_ + j] = v;
            out[wid * NP_ + j]    = 1.f / (1.f + expf(-v));
        }
    }
}

// ---------------------------------------------------------------------------
extern "C" void kernel_launch(void* const* d_in, const int* in_sizes, int n_in,
                              void* d_out, int out_size, void* d_ws, size_t ws_size,
                              hipStream_t stream)
{
    const float* motion_z = (const float*)d_in[0];
    const int*   tasks    = (const int*)d_in[1];
    const int*   tmask    = (const int*)d_in[2];
    const int*   pids     = (const int*)d_in[3];
    const float* phenos   = (const float*)d_in[4];
    const int*   pmask    = (const int*)d_in[5];
    const float* W1 = (const float*)d_in[6];
    const float* b1 = (const float*)d_in[7];
    const float* W2 = (const float*)d_in[8];
    const float* b2 = (const float*)d_in[9];
    const float* W3 = (const float*)d_in[10];
    const float* b3 = (const float*)d_in[11];

    char* ws = (char*)d_ws;
    float*          pt_sum = (float*)(ws + OFF_PTSUM);
    float*          cnt    = (float*)(ws + OFF_CNT);
    float*          tsum   = (float*)(ws + OFF_TSUM);
    float*          tcnt   = (float*)(ws + OFF_TCNT);
    unsigned*       fmax   = (unsigned*)(ws + OFF_FMAX);
    unsigned short* fphi   = (unsigned short*)(ws + OFF_FPHI);
    unsigned short* fplo   = (unsigned short*)(ws + OFF_FPLO);
    unsigned short* w1thi  = (unsigned short*)(ws + OFF_W1THI);
    unsigned short* w1tlo  = (unsigned short*)(ws + OFF_W1TLO);
    unsigned short* h1hi   = (unsigned short*)(ws + OFF_H1HI);
    unsigned short* h1lo   = (unsigned short*)(ws + OFF_H1LO);
    unsigned short* w2thi  = (unsigned short*)(ws + OFF_W2THI);
    unsigned short* w2tlo  = (unsigned short*)(ws + OFF_W2TLO);
    float*          h2     = (float*)(ws + OFF_H2);

    float* out    = (float*)d_out;
    float* uni    = out + P_ * NP_;
    float* latent = out + 2 * P_ * NP_;

    // Node 1: single memset covers pt_sum | cnt | tsum | tcnt | fmax
    hipMemsetAsync(ws, 0, ZERO_BYTES, stream);

    // Node 2: block-compaction scatter (782 chunks of 256 rows)
    scatter_pt<<<782, 256, 0, stream>>>(motion_z, tasks, tmask, pids, pmask,
                                        pt_sum, cnt, fmax);
    // Node 3: task-sum partials + both weight transposes (fused)
    mid_fused<<<125 + 6144, 256, 0, stream>>>(pt_sum, cnt, tsum, tcnt,
                                              W1, W2, w1thi, w1tlo, w2thi, w2tlo);
    // Node 4: finalize fingerprint (vec8) + pheno gather
    finalize_fused<<<1024 + (P_ * NP_ + 255) / 256, 256, 0, stream>>>(
        pt_sum, cnt, tsum, tcnt, fmax, phenos, fphi, fplo, uni);

    // Node 5: GEMM1 fingerprint[2048,1024] @ W1 -> h1 (relu, bf16 hi/lo out)
    gemm_split<0><<<dim3(16, 16), 256, 0, stream>>>(
        fphi, fplo, w1thi, w1tlo, b1, nullptr, h1hi, h1lo, 1024);
    // Node 6: GEMM2 h1[2048,2048] @ W2 -> h2 (relu, f32 out)
    gemm_split<1><<<dim3(16, 16), 256, 0, stream>>>(
        h1hi, h1lo, w2thi, w2tlo, b2, h2, nullptr, nullptr, H_);

    // Node 7: head + sigmoid
    out_head<<<P_ / 4, 256, 0, stream>>>(h2, W3, b3, out, latent);
}